// Round 1
// baseline (1349.524 us; speedup 1.0000x reference)
//
#include <hip/hip_runtime.h>
#include <stdint.h>

#define HEADS 8
#define DM 512
#define TT 12
#define WIN 3
#define NN 325
#define BB 4
#define HD 64
#define MROWS (BB*TT*NN)                  // 15600 rows for QKV gemm
static const size_t QKV_ELE = (size_t)MROWS * DM;  // 7,987,200 elems per q/k/v tensor

typedef unsigned short u16;
typedef __attribute__((ext_vector_type(8))) short bf16x8;
typedef __attribute__((ext_vector_type(4))) float f32x4;

static __device__ __forceinline__ u16 f2bf(float f) {
  uint32_t u = __float_as_uint(f);
  u += 0x7fff + ((u >> 16) & 1);   // RNE
  return (u16)(u >> 16);
}
static __device__ __forceinline__ float bf2f(u16 h) {
  return __uint_as_float((uint32_t)h << 16);
}

// ---------------- pack kernels: f32 -> bf16 ----------------
__global__ void pack_x(const float* __restrict__ xin, u16* __restrict__ xb) {
  int n4 = (int)(QKV_ELE / 4);
  for (int i = blockIdx.x * blockDim.x + threadIdx.x; i < n4; i += gridDim.x * blockDim.x) {
    float4 v = ((const float4*)xin)[i];
    uint32_t a0 = (uint32_t)f2bf(v.x) | ((uint32_t)f2bf(v.y) << 16);
    uint32_t a1 = (uint32_t)f2bf(v.z) | ((uint32_t)f2bf(v.w) << 16);
    ((uint2*)xb)[i] = make_uint2(a0, a1);
  }
}

__global__ void pack_w(const float* __restrict__ Wq, const float* __restrict__ Wk,
                       const float* __restrict__ Wv, const float* __restrict__ bq,
                       const float* __restrict__ bk, const float* __restrict__ bv,
                       u16* __restrict__ Wb, float* __restrict__ biasc) {
  int i = blockIdx.x * blockDim.x + threadIdx.x;
  const int n4 = (3 * 512 * 512) / 4;   // 196608
  if (i < n4) {
    int j = i << 2;
    int which = j >> 18;                 // 512*512 = 2^18
    int off4 = i & ((512 * 512 / 4) - 1);
    const float* src = which == 0 ? Wq : (which == 1 ? Wk : Wv);
    float4 v = ((const float4*)src)[off4];
    uint32_t a0 = (uint32_t)f2bf(v.x) | ((uint32_t)f2bf(v.y) << 16);
    uint32_t a1 = (uint32_t)f2bf(v.z) | ((uint32_t)f2bf(v.w) << 16);
    ((uint2*)Wb)[i] = make_uint2(a0, a1);
  }
  if (i < 1536 / 4) {
    int j = i << 2;
    int which = j >> 9;
    int off4 = i & 127;
    const float* src = which == 0 ? bq : (which == 1 ? bk : bv);
    ((float4*)biasc)[i] = ((const float4*)src)[off4];
  }
}

// ---------------- fused QKV projection GEMM ----------------
// C[m][e] = sum_d x[m][d] * W[e][d] + bias[e]   (m = (b*T+t)*N+n, e in [0,1536))
// 128x128 tile, BK=32, 4 waves in 2x2, 16x16x32 bf16 MFMA.
__global__ __launch_bounds__(256) void proj_gemm(
    const u16* __restrict__ A,      // [M][512] bf16
    const u16* __restrict__ W,      // [1536][512] bf16
    const float* __restrict__ bias, // [1536]
    u16* __restrict__ qkv)          // 3 x [B][T][H][N][64] bf16
{
  __shared__ u16 sA[128 * 32];
  __shared__ u16 sB[128 * 32];
  const int m0 = blockIdx.x * 128;
  const int n0 = blockIdx.y * 128;
  const int tid = threadIdx.x;
  const int lane = tid & 63;
  const int wid = tid >> 6;
  const int wr = wid >> 1, wc = wid & 1;

  f32x4 acc[4][4] = {};

  const int srow = tid >> 2;
  const int scol = (tid & 3) * 8;

  for (int k0 = 0; k0 < 512; k0 += 32) {
    __syncthreads();
#pragma unroll
    for (int i = 0; i < 2; ++i) {
      int row = i * 64 + srow;
      int gm = m0 + row; if (gm >= MROWS) gm = MROWS - 1;
      *(bf16x8*)&sA[row * 32 + scol] = *(const bf16x8*)&A[(size_t)gm * 512 + k0 + scol];
      *(bf16x8*)&sB[row * 32 + scol] = *(const bf16x8*)&W[(size_t)(n0 + row) * 512 + k0 + scol];
    }
    __syncthreads();
    bf16x8 af[4], bfr[4];
#pragma unroll
    for (int mi = 0; mi < 4; ++mi)
      af[mi] = *(const bf16x8*)&sA[(wr * 64 + mi * 16 + (lane & 15)) * 32 + (lane >> 4) * 8];
#pragma unroll
    for (int ni = 0; ni < 4; ++ni)
      bfr[ni] = *(const bf16x8*)&sB[(wc * 64 + ni * 16 + (lane & 15)) * 32 + (lane >> 4) * 8];
#pragma unroll
    for (int mi = 0; mi < 4; ++mi)
#pragma unroll
      for (int ni = 0; ni < 4; ++ni)
        acc[mi][ni] = __builtin_amdgcn_mfma_f32_16x16x32_bf16(af[mi], bfr[ni], acc[mi][ni], 0, 0, 0);
  }

  // epilogue: +bias, scatter into q/k/v [B][T][H][N][64] bf16
  const int lr = (lane >> 4) * 4;
  const int lc = lane & 15;
#pragma unroll
  for (int mi = 0; mi < 4; ++mi) {
#pragma unroll
    for (int j = 0; j < 4; ++j) {
      int gm = m0 + wr * 64 + mi * 16 + lr + j;
      if (gm < MROWS) {
        int b = gm / (TT * NN);
        int rem = gm - b * (TT * NN);
        int t = rem / NN;
        int n = rem - t * NN;
#pragma unroll
        for (int ni = 0; ni < 4; ++ni) {
          int e = n0 + wc * 64 + ni * 16 + lc;
          float val = acc[mi][ni][j] + bias[e];
          int which = e >> 9;
          int h = (e >> 6) & 7;
          int d = e & 63;
          qkv[(size_t)which * QKV_ELE + ((((size_t)(b * TT + t) * HEADS + h) * NN + n) << 6) + d] = f2bf(val);
        }
      }
    }
  }
}

// ---------------- attention: one block per (b,t,h,ti), thread-per-row online softmax ----------------
#define CJ 64
__global__ __launch_bounds__(384) void attn(
    const u16* __restrict__ qkv,
    const float* __restrict__ adj,
    u16* __restrict__ hcat)          // [B][36][N][512] bf16, w = ti*12 + t
{
  __shared__ float sK[CJ * 64];
  __shared__ float sV[CJ * 64];
  int idx = blockIdx.x;                 // ((b*12+t)*3 + ti)*8 + h
  int h = idx & 7;
  int rest = idx >> 3;
  int ti = rest % 3;
  int bt = rest / 3;
  int t = bt % TT;
  int b = bt / TT;

  const int c_kv[3]  = {9, 7, 6};       // cumulative k/v shifts: -3,-5,-6 mod 12
  const int c_adj[3] = {9, 10, 11};     // per-window adj shifts: -3,-2,-1 mod 12
  const float qsc[3] = {0.125f, 0.015625f, 0.001953125f}; // scale^(ti+1), scale=1/8
  int t_kv = (t + c_kv[ti]) % TT;
  int t_adj = (t + c_adj[ti]) % TT;

  int tid = threadIdx.x;
  int n = tid < NN ? tid : NN - 1;

  const u16* qptr = qkv + ((((size_t)(b * TT + t) * HEADS + h) * NN + n) << 6);
  const u16* kbase = qkv + QKV_ELE + ((((size_t)(b * TT + t_kv) * HEADS + h) * NN) << 6);
  const u16* vbase = qkv + 2 * QKV_ELE + ((((size_t)(b * TT + t_kv) * HEADS + h) * NN) << 6);
  const float* adjrow = adj + ((size_t)(b * TT + t_adj) * NN + n) * NN;

  float q[64];
  float sc = qsc[ti];
#pragma unroll
  for (int d = 0; d < 64; ++d) q[d] = bf2f(qptr[d]) * sc;
  float o[64];
#pragma unroll
  for (int d = 0; d < 64; ++d) o[d] = 0.f;
  float mrun = -1e30f, lrun = 0.f;

  for (int j0 = 0; j0 < NN; j0 += CJ) {
    int cnt = NN - j0; if (cnt > CJ) cnt = CJ;
    __syncthreads();
    for (int i = tid; i < cnt * 64; i += 384) {
      sK[i] = bf2f(kbase[j0 * 64 + i]);
      sV[i] = bf2f(vbase[j0 * 64 + i]);
    }
    __syncthreads();
    for (int jj = 0; jj < cnt; ++jj) {
      const float* kk = &sK[jj * 64];
      float p0 = 0, p1 = 0, p2 = 0, p3 = 0;
#pragma unroll
      for (int u = 0; u < 64; u += 4) {
        p0 += q[u] * kk[u];
        p1 += q[u + 1] * kk[u + 1];
        p2 += q[u + 2] * kk[u + 2];
        p3 += q[u + 3] * kk[u + 3];
      }
      float s = (p0 + p1) + (p2 + p3);
      float aval = (s + 1.0f) * adjrow[j0 + jj];
      float mn = fmaxf(mrun, aval);
      float p = __expf(aval - mn);
      if (aval > mrun) {
        float alpha = __expf(mrun - mn);
        lrun *= alpha;
#pragma unroll
        for (int d = 0; d < 64; ++d) o[d] *= alpha;
        mrun = mn;
      }
      lrun += p;
      const float* vv = &sV[jj * 64];
#pragma unroll
      for (int d = 0; d < 64; ++d) o[d] += p * vv[d];
    }
  }
  if (tid < NN) {
    float inv = 1.0f / lrun;
    u16* optr = hcat + (((size_t)(b * 36 + ti * TT + t) * NN + n) << 9) + h * 64;
#pragma unroll
    for (int d = 0; d < 64; ++d) optr[d] = f2bf(o[d] * inv);
  }
}

// ---------------- temporal mix + residual + LayerNorm ----------------
// one block per (b,n): stage h[36][512] in LDS, produce 12 output rows
__global__ __launch_bounds__(256) void mix_ln(
    const u16* __restrict__ hcat,
    const float* __restrict__ Wd,   // [12][36]
    const float* __restrict__ bd,   // [12]
    const float* __restrict__ x,
    const float* __restrict__ gamma,
    const float* __restrict__ beta,
    float* __restrict__ out)
{
  __shared__ float sH[36 * 512];
  __shared__ float sWd[12 * 36];
  __shared__ float sred[8];
  int bn = blockIdx.x;
  int b = bn / NN, n = bn - b * NN;
  int tid = threadIdx.x;
  int lane = tid & 63, wid = tid >> 6;

  for (int i = tid; i < 12 * 36; i += 256) sWd[i] = Wd[i];
  for (int i = tid; i < 36 * 512; i += 256) {
    int w = i >> 9, d = i & 511;
    sH[i] = bf2f(hcat[(((size_t)(b * 36 + w) * NN + n) << 9) + d]);
  }
  __syncthreads();

  for (int t = 0; t < TT; ++t) {
    float a0 = 0.f, a1 = 0.f;
#pragma unroll
    for (int w = 0; w < 36; ++w) {
      float wv = sWd[t * 36 + w];
      a0 += sH[(w << 9) + tid] * wv;
      a1 += sH[(w << 9) + 256 + tid] * wv;
    }
    size_t xoff = ((size_t)(b * TT + t) * NN + n) << 9;
    float bdt = bd[t];
    float y0 = a0 + bdt + x[xoff + tid];
    float y1 = a1 + bdt + x[xoff + 256 + tid];
    float s = y0 + y1, ss = y0 * y0 + y1 * y1;
#pragma unroll
    for (int off = 32; off > 0; off >>= 1) {
      s += __shfl_down(s, off);
      ss += __shfl_down(ss, off);
    }
    if (lane == 0) { sred[wid * 2] = s; sred[wid * 2 + 1] = ss; }
    __syncthreads();
    float stot = sred[0] + sred[2] + sred[4] + sred[6];
    float sstot = sred[1] + sred[3] + sred[5] + sred[7];
    float mu = stot * (1.0f / 512.0f);
    float var = sstot * (1.0f / 512.0f) - mu * mu;
    float rstd = rsqrtf(var + 1e-5f);
    out[xoff + tid] = (y0 - mu) * rstd * gamma[tid] + beta[tid];
    out[xoff + 256 + tid] = (y1 - mu) * rstd * gamma[tid + 256] + beta[tid + 256];
    __syncthreads();
  }
}

extern "C" void kernel_launch(void* const* d_in, const int* in_sizes, int n_in,
                              void* d_out, int out_size, void* d_ws, size_t ws_size,
                              hipStream_t stream) {
  const float* x     = (const float*)d_in[0];
  const float* adj   = (const float*)d_in[1];
  // d_in[2] = s_adj: unused by the reference
  const float* Wq    = (const float*)d_in[3];
  const float* bq    = (const float*)d_in[4];
  const float* Wk    = (const float*)d_in[5];
  const float* bk    = (const float*)d_in[6];
  const float* Wv    = (const float*)d_in[7];
  const float* bv    = (const float*)d_in[8];
  const float* Wd    = (const float*)d_in[9];
  const float* bd    = (const float*)d_in[10];
  const float* gamma = (const float*)d_in[11];
  const float* beta  = (const float*)d_in[12];
  float* out = (float*)d_out;

  char* ws = (char*)d_ws;
  size_t off = 0;
  auto alloc = [&](size_t bytes) {
    void* p = ws + off;
    off += (bytes + 255) & ~(size_t)255;
    return p;
  };
  u16* xb     = (u16*)alloc(QKV_ELE * 2);        // x in bf16
  u16* Wb     = (u16*)alloc(1536 * 512 * 2);     // [Wq;Wk;Wv] bf16
  float* bias = (float*)alloc(1536 * 4);         // [bq;bk;bv]
  u16* qkv    = (u16*)alloc(3 * QKV_ELE * 2);    // q,k,v bf16 (B,T,H,N,64)
  u16* hcat   = (u16*)alloc(3 * QKV_ELE * 2);    // (B,36,N,512) bf16

  pack_x<<<dim3(2048), dim3(256), 0, stream>>>(x, xb);
  pack_w<<<dim3(768), dim3(256), 0, stream>>>(Wq, Wk, Wv, bq, bk, bv, Wb, bias);
  proj_gemm<<<dim3((MROWS + 127) / 128, 1536 / 128), dim3(256), 0, stream>>>(xb, Wb, bias, qkv);
  attn<<<dim3(BB * TT * WIN * HEADS), dim3(384), 0, stream>>>(qkv, adj, hcat);
  mix_ln<<<dim3(BB * NN), dim3(256), 0, stream>>>(hcat, Wd, bd, x, gamma, beta, out);
}

// Round 2
// 278.163 us; speedup vs baseline: 4.8516x; 4.8516x over previous
//
#include <hip/hip_runtime.h>
#include <stdint.h>

#define HEADS 8
#define DM 512
#define TT 12
#define WIN 3
#define NN 325
#define BB 4
#define HD 64
#define MROWS (BB*TT*NN)                  // 15600 rows for QKV gemm
#define VTS 328                           // padded VT row stride (16B-aligned frags)
static const size_t QKV_ELE = (size_t)MROWS * DM;  // 7,987,200 elems per q/k/v tensor

typedef unsigned short u16;
typedef __attribute__((ext_vector_type(8))) short bf16x8;
typedef __attribute__((ext_vector_type(4))) float f32x4;

#define MFMA(a,b,c) __builtin_amdgcn_mfma_f32_16x16x32_bf16(a, b, c, 0, 0, 0)

#if defined(__has_builtin)
#if __has_builtin(__builtin_amdgcn_exp2f)
#define EXP2(x) __builtin_amdgcn_exp2f(x)
#endif
#endif
#ifndef EXP2
#define EXP2(x) exp2f(x)
#endif

static __device__ __forceinline__ u16 f2bf(float f) {
  uint32_t u = __float_as_uint(f);
  u += 0x7fff + ((u >> 16) & 1);   // RNE
  return (u16)(u >> 16);
}
// pack two f32 -> one u32 of 2 bf16 (truncating), lo in low half
static __device__ __forceinline__ uint32_t pk2(float hi, float lo) {
  return __builtin_amdgcn_perm(__float_as_uint(hi), __float_as_uint(lo), 0x07060302);
}
static __device__ __forceinline__ float bf2f(u16 h) {
  return __uint_as_float((uint32_t)h << 16);
}

// ---------------- pack W (RNE) + bias concat ----------------
__global__ void pack_w(const float* __restrict__ Wq, const float* __restrict__ Wk,
                       const float* __restrict__ Wv, const float* __restrict__ bq,
                       const float* __restrict__ bk, const float* __restrict__ bv,
                       u16* __restrict__ Wb, float* __restrict__ biasc) {
  int i = blockIdx.x * blockDim.x + threadIdx.x;
  const int n4 = (3 * 512 * 512) / 4;   // 196608
  if (i < n4) {
    int j = i << 2;
    int which = j >> 18;                 // 512*512 = 2^18
    int off4 = i & ((512 * 512 / 4) - 1);
    const float* src = which == 0 ? Wq : (which == 1 ? Wk : Wv);
    float4 v = ((const float4*)src)[off4];
    uint32_t a0 = (uint32_t)f2bf(v.x) | ((uint32_t)f2bf(v.y) << 16);
    uint32_t a1 = (uint32_t)f2bf(v.z) | ((uint32_t)f2bf(v.w) << 16);
    ((uint2*)Wb)[i] = make_uint2(a0, a1);
  }
  if (i < 1536 / 4) {
    int j = i << 2;
    int which = j >> 9;
    int off4 = i & 127;
    const float* src = which == 0 ? bq : (which == 1 ? bk : bv);
    ((float4*)biasc)[i] = ((const float4*)src)[off4];
  }
}

// ---------------- fused QKV projection GEMM (f32 x converted inline) ----------------
__global__ __launch_bounds__(256) void proj_gemm(
    const float* __restrict__ x,    // [M][512] f32
    const u16* __restrict__ W,      // [1536][512] bf16
    const float* __restrict__ bias, // [1536]
    u16* __restrict__ qkv)          // 3 x [B][T][H][N][64] bf16
{
  __shared__ u16 sA[128 * 32];
  __shared__ u16 sB[128 * 32];
  const int m0 = blockIdx.x * 128;
  const int n0 = blockIdx.y * 128;
  const int tid = threadIdx.x;
  const int lane = tid & 63;
  const int wid = tid >> 6;
  const int wr = wid >> 1, wc = wid & 1;

  f32x4 acc[4][4] = {};

  const int srow = tid >> 2;
  const int scol = (tid & 3) * 8;

  for (int k0 = 0; k0 < 512; k0 += 32) {
    __syncthreads();
#pragma unroll
    for (int i = 0; i < 2; ++i) {
      int row = i * 64 + srow;
      int gm = m0 + row; if (gm >= MROWS) gm = MROWS - 1;
      const float* xa = x + (size_t)gm * 512 + k0 + scol;
      float4 f0 = *(const float4*)xa;
      float4 f1 = *(const float4*)(xa + 4);
      uint4 u;
      u.x = pk2(f0.y, f0.x);
      u.y = pk2(f0.w, f0.z);
      u.z = pk2(f1.y, f1.x);
      u.w = pk2(f1.w, f1.z);
      *(uint4*)&sA[row * 32 + scol] = u;
      *(bf16x8*)&sB[row * 32 + scol] = *(const bf16x8*)&W[(size_t)(n0 + row) * 512 + k0 + scol];
    }
    __syncthreads();
    bf16x8 af[4], bfr[4];
#pragma unroll
    for (int mi = 0; mi < 4; ++mi)
      af[mi] = *(const bf16x8*)&sA[(wr * 64 + mi * 16 + (lane & 15)) * 32 + (lane >> 4) * 8];
#pragma unroll
    for (int ni = 0; ni < 4; ++ni)
      bfr[ni] = *(const bf16x8*)&sB[(wc * 64 + ni * 16 + (lane & 15)) * 32 + (lane >> 4) * 8];
#pragma unroll
    for (int mi = 0; mi < 4; ++mi)
#pragma unroll
      for (int ni = 0; ni < 4; ++ni)
        acc[mi][ni] = MFMA(af[mi], bfr[ni], acc[mi][ni]);
  }

  const int lr = (lane >> 4) * 4;
  const int lc = lane & 15;
#pragma unroll
  for (int mi = 0; mi < 4; ++mi) {
#pragma unroll
    for (int j = 0; j < 4; ++j) {
      int gm = m0 + wr * 64 + mi * 16 + lr + j;
      if (gm < MROWS) {
        int b = gm / (TT * NN);
        int rem = gm - b * (TT * NN);
        int t = rem / NN;
        int n = rem - t * NN;
#pragma unroll
        for (int ni = 0; ni < 4; ++ni) {
          int e = n0 + wc * 64 + ni * 16 + lc;
          float val = acc[mi][ni][j] + bias[e];
          int which = e >> 9;
          int h = (e >> 6) & 7;
          int d = e & 63;
          qkv[(size_t)which * QKV_ELE + ((((size_t)(b * TT + t) * HEADS + h) * NN + n) << 6) + d] = f2bf(val);
        }
      }
    }
  }
}

// ---------------- V transpose: [slab][325][64] -> [slab][64][VTS] ----------------
__global__ __launch_bounds__(256) void vt_pack(const u16* __restrict__ v, u16* __restrict__ vt) {
  __shared__ u16 sv[325 * 66];
  int slab = blockIdx.x;            // (b*T + t)*H + h
  const u16* src = v + (size_t)slab * 325 * 64;
  u16* dst = vt + (size_t)slab * 64 * VTS;
  int tid = threadIdx.x;
  for (int i = tid; i < 325 * 16; i += 256) {
    int n = i >> 4, dd = (i & 15) * 4;
    uint2 w = *(const uint2*)(src + n * 64 + dd);
    *(uint*)(sv + n * 66 + dd) = w.x;
    *(uint*)(sv + n * 66 + dd + 2) = w.y;
  }
  __syncthreads();
  for (int d = 0; d < 64; ++d)
    for (int n = tid; n < 325; n += 256)
      dst[d * VTS + n] = sv[n * 66 + d];
}

// ---------------- MFMA attention ----------------
// One wave = 64 query rows of one (b,t,ti,h). 4 subtiles of 16 q-rows.
// S^T = mfma(K_perm, Q): with K rows permuted rmap(r)=8*(r>>2)+(r&3), lane (qi,g)
// holds P for keys 8g..8g+7 — exactly the A-frag of mfma_16x16x32 for PV.
// Fixed softmax shift (m=8): p=exp(s-8), no online rescale.
__global__ __launch_bounds__(256, 2) void attn(
    const u16* __restrict__ qkv,    // q at 0, k at QKV_ELE
    const u16* __restrict__ vt,     // [384][64][VTS]
    const float* __restrict__ adj,
    u16* __restrict__ hcat)         // [B][36][N][512] bf16
{
  const int wid = threadIdx.x >> 6;
  const int lane = threadIdx.x & 63;
  const int qi = lane & 15;
  const int g = lane >> 4;

  int wg = blockIdx.x * 4 + wid;     // 0..6911
  int qt = wg % 6;
  int idx = wg / 6;
  int h = idx & 7;
  int rest = idx >> 3;
  int ti = rest % 3;
  int bt = rest / 3;
  int t = bt % TT;
  int b = bt / TT;

  const int c_kv[3]  = {9, 7, 6};       // k/v cumulative shifts: t-3, t-5, t-6
  const int c_adj[3] = {9, 10, 11};     // adj shifts: t-3, t-2, t-1
  const float qscA[3] = {0.125f, 0.015625f, 0.001953125f};
  int t_kv = (t + c_kv[ti]) % TT;
  int t_adj = (t + c_adj[ti]) % TT;
  float qsc = qscA[ti];

  int q0 = qt * 64;

  const u16* qbase  = qkv + ((((size_t)(b * TT + t) * HEADS + h) * NN) << 6);
  const u16* kbase  = qkv + QKV_ELE + ((((size_t)(b * TT + t_kv) * HEADS + h) * NN) << 6);
  const u16* vtbase = vt + (size_t)((b * TT + t_kv) * HEADS + h) * 64 * VTS;
  const float* adjbase = adj + (size_t)(b * TT + t_adj) * NN * NN;

  // Q fragments (B-operand): Q[q0+s*16+qi][kk*32 + g*8 + e]
  bf16x8 qf[4][2];
  const float* ar[4];
#pragma unroll
  for (int s = 0; s < 4; ++s) {
    int qr = q0 + s * 16 + qi; if (qr > NN - 1) qr = NN - 1;
    const u16* qp = qbase + qr * 64 + g * 8;
    qf[s][0] = *(const bf16x8*)qp;
    qf[s][1] = *(const bf16x8*)(qp + 32);
    ar[s] = adjbase + (size_t)qr * NN;
  }

  f32x4 acc[4][4] = {};    // [sub][dtile]
  float lsum[4] = {0.f, 0.f, 0.f, 0.f};

  const float LG = 1.44269504f;
  const float C8 = -11.5415603f;   // -8*log2(e)
  const int rmap = ((qi >> 2) << 3) + (qi & 3);
  const f32x4 z4 = {0.f, 0.f, 0.f, 0.f};

  for (int kt = 0; kt < 10; ++kt) {
    int K0 = kt * 32;
    const u16* kp0 = kbase + (K0 + rmap) * 64 + g * 8;
    const u16* kp1 = kp0 + 4 * 64;
    bf16x8 ka0 = *(const bf16x8*)kp0;
    bf16x8 ka1 = *(const bf16x8*)(kp0 + 32);
    bf16x8 kb0 = *(const bf16x8*)kp1;
    bf16x8 kb1 = *(const bf16x8*)(kp1 + 32);
    bf16x8 vf[4];
#pragma unroll
    for (int dt = 0; dt < 4; ++dt)
      vf[dt] = *(const bf16x8*)(vtbase + (dt * 16 + qi) * VTS + K0 + g * 8);
#pragma unroll
    for (int s = 0; s < 4; ++s) {
      f32x4 s0 = MFMA(ka0, qf[s][0], z4);
      s0 = MFMA(ka1, qf[s][1], s0);
      f32x4 s1 = MFMA(kb0, qf[s][0], z4);
      s1 = MFMA(kb1, qf[s][1], s1);
      const float* a8 = ar[s] + K0 + g * 8;
      float p[8];
#pragma unroll
      for (int j = 0; j < 4; ++j) {
        float av = a8[j];
        float z = __builtin_fmaf(s0[j], av * qsc, av);   // (s*qsc + 1)*adj
        p[j] = EXP2(__builtin_fmaf(z, LG, C8));          // exp(z - 8)
      }
#pragma unroll
      for (int j = 0; j < 4; ++j) {
        float av = a8[4 + j];
        float z = __builtin_fmaf(s1[j], av * qsc, av);
        p[4 + j] = EXP2(__builtin_fmaf(z, LG, C8));
      }
      lsum[s] += ((p[0] + p[1]) + (p[2] + p[3])) + ((p[4] + p[5]) + (p[6] + p[7]));
      union { uint32_t u[4]; bf16x8 v; } pu;
      pu.u[0] = pk2(p[1], p[0]);
      pu.u[1] = pk2(p[3], p[2]);
      pu.u[2] = pk2(p[5], p[4]);
      pu.u[3] = pk2(p[7], p[6]);
#pragma unroll
      for (int dt = 0; dt < 4; ++dt)
        acc[s][dt] = MFMA(pu.v, vf[dt], acc[s][dt]);
    }
  }

  // ---- tail: keys 320..324 ----
  {
    const int T0 = 320;
    int r0 = T0 + rmap;     if (r0 > NN - 1) r0 = NN - 1;
    int r1 = T0 + rmap + 4; if (r1 > NN - 1) r1 = NN - 1;
    const u16* kp0 = kbase + r0 * 64 + g * 8;
    const u16* kp1 = kbase + r1 * 64 + g * 8;
    bf16x8 ka0 = *(const bf16x8*)kp0;
    bf16x8 ka1 = *(const bf16x8*)(kp0 + 32);
    bf16x8 kb0 = *(const bf16x8*)kp1;
    bf16x8 kb1 = *(const bf16x8*)(kp1 + 32);
    bf16x8 vf[4];
#pragma unroll
    for (int dt = 0; dt < 4; ++dt) {
      union { u16 e[8]; bf16x8 v; } vu;
#pragma unroll
      for (int e = 0; e < 8; ++e) {
        int col = T0 + g * 8 + e; if (col > NN - 1) col = NN - 1;
        vu.e[e] = vtbase[(dt * 16 + qi) * VTS + col];
      }
      vf[dt] = vu.v;
    }
#pragma unroll
    for (int s = 0; s < 4; ++s) {
      f32x4 s0 = MFMA(ka0, qf[s][0], z4);
      s0 = MFMA(ka1, qf[s][1], s0);
      f32x4 s1 = MFMA(kb0, qf[s][0], z4);
      s1 = MFMA(kb1, qf[s][1], s1);
      float p[8];
#pragma unroll
      for (int j = 0; j < 4; ++j) {
        int ko = g * 8 + j;
        float av = ar[s][T0 + (ko > 4 ? 4 : ko)];
        float z = __builtin_fmaf(s0[j], av * qsc, av);
        float pv = EXP2(__builtin_fmaf(z, LG, C8));
        p[j] = (ko < 5) ? pv : 0.f;
      }
#pragma unroll
      for (int j = 0; j < 4; ++j) {
        int ko = g * 8 + 4 + j;
        float av = ar[s][T0 + (ko > 4 ? 4 : ko)];
        float z = __builtin_fmaf(s1[j], av * qsc, av);
        float pv = EXP2(__builtin_fmaf(z, LG, C8));
        p[4 + j] = (ko < 5) ? pv : 0.f;
      }
      lsum[s] += ((p[0] + p[1]) + (p[2] + p[3])) + ((p[4] + p[5]) + (p[6] + p[7]));
      union { uint32_t u[4]; bf16x8 v; } pu;
      pu.u[0] = pk2(p[1], p[0]);
      pu.u[1] = pk2(p[3], p[2]);
      pu.u[2] = pk2(p[5], p[4]);
      pu.u[3] = pk2(p[7], p[6]);
#pragma unroll
      for (int dt = 0; dt < 4; ++dt)
        acc[s][dt] = MFMA(pu.v, vf[dt], acc[s][dt]);
    }
  }

  // ---- epilogue: normalize + store ----
  size_t hb = ((size_t)(b * 36 + ti * TT + t) * NN) << 9;
#pragma unroll
  for (int s = 0; s < 4; ++s) {
    float v = lsum[s];
    v += __shfl_xor(v, 16);
    v += __shfl_xor(v, 32);
    float linv = 1.0f / v;
#pragma unroll
    for (int j = 0; j < 4; ++j) {
      float li = __shfl(linv, g * 4 + j);      // lane (g*4+j) holds l for q-local g*4+j
      int qrow = q0 + s * 16 + 4 * g + j;
      if (qrow < NN) {
        u16* op = hcat + hb + ((size_t)qrow << 9) + h * 64 + qi;
#pragma unroll
        for (int dt = 0; dt < 4; ++dt)
          op[dt * 16] = f2bf(acc[s][dt][j] * li);
      }
    }
  }
}

// ---------------- temporal mix + residual + LayerNorm ----------------
__global__ __launch_bounds__(256) void mix_ln(
    const u16* __restrict__ hcat,
    const float* __restrict__ Wd,   // [12][36]
    const float* __restrict__ bd,   // [12]
    const float* __restrict__ x,
    const float* __restrict__ gamma,
    const float* __restrict__ beta,
    float* __restrict__ out)
{
  __shared__ float sH[36 * 512];
  __shared__ float sWd[12 * 36];
  __shared__ float sred[8];
  int bn = blockIdx.x;
  int b = bn / NN, n = bn - b * NN;
  int tid = threadIdx.x;
  int lane = tid & 63, wid = tid >> 6;

  for (int i = tid; i < 12 * 36; i += 256) sWd[i] = Wd[i];
  for (int i = tid; i < 36 * 512; i += 256) {
    int w = i >> 9, d = i & 511;
    sH[i] = bf2f(hcat[(((size_t)(b * 36 + w) * NN + n) << 9) + d]);
  }
  __syncthreads();

  for (int t = 0; t < TT; ++t) {
    float a0 = 0.f, a1 = 0.f;
#pragma unroll
    for (int w = 0; w < 36; ++w) {
      float wv = sWd[t * 36 + w];
      a0 += sH[(w << 9) + tid] * wv;
      a1 += sH[(w << 9) + 256 + tid] * wv;
    }
    size_t xoff = ((size_t)(b * TT + t) * NN + n) << 9;
    float bdt = bd[t];
    float y0 = a0 + bdt + x[xoff + tid];
    float y1 = a1 + bdt + x[xoff + 256 + tid];
    float s = y0 + y1, ss = y0 * y0 + y1 * y1;
#pragma unroll
    for (int off = 32; off > 0; off >>= 1) {
      s += __shfl_down(s, off);
      ss += __shfl_down(ss, off);
    }
    if (lane == 0) { sred[wid * 2] = s; sred[wid * 2 + 1] = ss; }
    __syncthreads();
    float stot = sred[0] + sred[2] + sred[4] + sred[6];
    float sstot = sred[1] + sred[3] + sred[5] + sred[7];
    float mu = stot * (1.0f / 512.0f);
    float var = sstot * (1.0f / 512.0f) - mu * mu;
    float rstd = rsqrtf(var + 1e-5f);
    out[xoff + tid] = (y0 - mu) * rstd * gamma[tid] + beta[tid];
    out[xoff + 256 + tid] = (y1 - mu) * rstd * gamma[tid + 256] + beta[tid + 256];
    __syncthreads();
  }
}

extern "C" void kernel_launch(void* const* d_in, const int* in_sizes, int n_in,
                              void* d_out, int out_size, void* d_ws, size_t ws_size,
                              hipStream_t stream) {
  const float* x     = (const float*)d_in[0];
  const float* adj   = (const float*)d_in[1];
  // d_in[2] = s_adj: unused by the reference
  const float* Wq    = (const float*)d_in[3];
  const float* bq    = (const float*)d_in[4];
  const float* Wk    = (const float*)d_in[5];
  const float* bk    = (const float*)d_in[6];
  const float* Wv    = (const float*)d_in[7];
  const float* bv    = (const float*)d_in[8];
  const float* Wd    = (const float*)d_in[9];
  const float* bd    = (const float*)d_in[10];
  const float* gamma = (const float*)d_in[11];
  const float* beta  = (const float*)d_in[12];
  float* out = (float*)d_out;

  char* ws = (char*)d_ws;
  size_t off = 0;
  auto alloc = [&](size_t bytes) {
    void* p = ws + off;
    off += (bytes + 255) & ~(size_t)255;
    return p;
  };
  u16* Wb     = (u16*)alloc(1536 * 512 * 2);         // [Wq;Wk;Wv] bf16
  float* bias = (float*)alloc(1536 * 4);             // [bq;bk;bv]
  u16* qkv    = (u16*)alloc(3 * QKV_ELE * 2);        // q,k,v bf16 (B,T,H,N,64)
  u16* hcat   = (u16*)alloc(3 * QKV_ELE * 2);        // (B,36,N,512) bf16
  u16* vtb    = (u16*)alloc((size_t)BB * TT * HEADS * 64 * VTS * 2);  // V^T padded

  pack_w<<<dim3(768), dim3(256), 0, stream>>>(Wq, Wk, Wv, bq, bk, bv, Wb, bias);
  proj_gemm<<<dim3((MROWS + 127) / 128, 1536 / 128), dim3(256), 0, stream>>>(x, Wb, bias, qkv);
  vt_pack<<<dim3(BB * TT * HEADS), dim3(256), 0, stream>>>(qkv + 2 * QKV_ELE, vtb);
  attn<<<dim3(BB * TT * WIN * HEADS * 6 / 4), dim3(256), 0, stream>>>(qkv, vtb, adj, hcat);
  mix_ln<<<dim3(BB * NN), dim3(256), 0, stream>>>(hcat, Wd, bd, x, gamma, beta, out);
}

// Round 3
// 260.076 us; speedup vs baseline: 5.1890x; 1.0695x over previous
//
#include <hip/hip_runtime.h>
#include <stdint.h>

#define HEADS 8
#define DM 512
#define TT 12
#define WIN 3
#define NN 325
#define BB 4
#define HD 64
#define MROWS (BB*TT*NN)                  // 15600 rows for QKV gemm
#define VTS 352                           // padded VT row stride; cols 325..351 zeroed
static const size_t QKV_ELE = (size_t)MROWS * DM;  // 7,987,200 elems per q/k/v tensor

typedef unsigned short u16;
typedef __attribute__((ext_vector_type(8))) short bf16x8;
typedef __attribute__((ext_vector_type(4))) float f32x4;

#define MFMA(a,b,c) __builtin_amdgcn_mfma_f32_16x16x32_bf16(a, b, c, 0, 0, 0)
#define EXP2(x) exp2f(x)

static __device__ __forceinline__ u16 f2bf(float f) {
  uint32_t u = __float_as_uint(f);
  u += 0x7fff + ((u >> 16) & 1);   // RNE
  return (u16)(u >> 16);
}
// pack two f32 -> one u32 of 2 bf16 (truncating), lo in low half
static __device__ __forceinline__ uint32_t pk2(float hi, float lo) {
  return __builtin_amdgcn_perm(__float_as_uint(hi), __float_as_uint(lo), 0x07060302);
}
static __device__ __forceinline__ float bf2f(u16 h) {
  return __uint_as_float((uint32_t)h << 16);
}

// ---------------- pack W (RNE) + bias concat ----------------
__global__ void pack_w(const float* __restrict__ Wq, const float* __restrict__ Wk,
                       const float* __restrict__ Wv, const float* __restrict__ bq,
                       const float* __restrict__ bk, const float* __restrict__ bv,
                       u16* __restrict__ Wb, float* __restrict__ biasc) {
  int i = blockIdx.x * blockDim.x + threadIdx.x;
  const int n4 = (3 * 512 * 512) / 4;   // 196608
  if (i < n4) {
    int j = i << 2;
    int which = j >> 18;                 // 512*512 = 2^18
    int off4 = i & ((512 * 512 / 4) - 1);
    const float* src = which == 0 ? Wq : (which == 1 ? Wk : Wv);
    float4 v = ((const float4*)src)[off4];
    uint32_t a0 = (uint32_t)f2bf(v.x) | ((uint32_t)f2bf(v.y) << 16);
    uint32_t a1 = (uint32_t)f2bf(v.z) | ((uint32_t)f2bf(v.w) << 16);
    ((uint2*)Wb)[i] = make_uint2(a0, a1);
  }
  if (i < 1536 / 4) {
    int j = i << 2;
    int which = j >> 9;
    int off4 = i & 127;
    const float* src = which == 0 ? bq : (which == 1 ? bk : bv);
    ((float4*)biasc)[i] = ((const float4*)src)[off4];
  }
}

// ---------------- fused QKV projection GEMM (f32 x converted inline) ----------------
__global__ __launch_bounds__(256) void proj_gemm(
    const float* __restrict__ x,    // [M][512] f32
    const u16* __restrict__ W,      // [1536][512] bf16
    const float* __restrict__ bias, // [1536]
    u16* __restrict__ qkv)          // 3 x [B][T][H][N][64] bf16
{
  __shared__ u16 sA[128 * 32];
  __shared__ u16 sB[128 * 32];
  const int m0 = blockIdx.x * 128;
  const int n0 = blockIdx.y * 128;
  const int tid = threadIdx.x;
  const int lane = tid & 63;
  const int wid = tid >> 6;
  const int wr = wid >> 1, wc = wid & 1;

  f32x4 acc[4][4] = {};

  const int srow = tid >> 2;
  const int scol = (tid & 3) * 8;

  for (int k0 = 0; k0 < 512; k0 += 32) {
    __syncthreads();
#pragma unroll
    for (int i = 0; i < 2; ++i) {
      int row = i * 64 + srow;
      int gm = m0 + row; if (gm >= MROWS) gm = MROWS - 1;
      const float* xa = x + (size_t)gm * 512 + k0 + scol;
      float4 f0 = *(const float4*)xa;
      float4 f1 = *(const float4*)(xa + 4);
      uint4 u;
      u.x = pk2(f0.y, f0.x);
      u.y = pk2(f0.w, f0.z);
      u.z = pk2(f1.y, f1.x);
      u.w = pk2(f1.w, f1.z);
      *(uint4*)&sA[row * 32 + scol] = u;
      *(bf16x8*)&sB[row * 32 + scol] = *(const bf16x8*)&W[(size_t)(n0 + row) * 512 + k0 + scol];
    }
    __syncthreads();
    bf16x8 af[4], bfr[4];
#pragma unroll
    for (int mi = 0; mi < 4; ++mi)
      af[mi] = *(const bf16x8*)&sA[(wr * 64 + mi * 16 + (lane & 15)) * 32 + (lane >> 4) * 8];
#pragma unroll
    for (int ni = 0; ni < 4; ++ni)
      bfr[ni] = *(const bf16x8*)&sB[(wc * 64 + ni * 16 + (lane & 15)) * 32 + (lane >> 4) * 8];
#pragma unroll
    for (int mi = 0; mi < 4; ++mi)
#pragma unroll
      for (int ni = 0; ni < 4; ++ni)
        acc[mi][ni] = MFMA(af[mi], bfr[ni], acc[mi][ni]);
  }

  const int lr = (lane >> 4) * 4;
  const int lc = lane & 15;
#pragma unroll
  for (int mi = 0; mi < 4; ++mi) {
#pragma unroll
    for (int j = 0; j < 4; ++j) {
      int gm = m0 + wr * 64 + mi * 16 + lr + j;
      if (gm < MROWS) {
        int b = gm / (TT * NN);
        int rem = gm - b * (TT * NN);
        int t = rem / NN;
        int n = rem - t * NN;
#pragma unroll
        for (int ni = 0; ni < 4; ++ni) {
          int e = n0 + wc * 64 + ni * 16 + lc;
          float val = acc[mi][ni][j] + bias[e];
          int which = e >> 9;
          int h = (e >> 6) & 7;
          int d = e & 63;
          qkv[(size_t)which * QKV_ELE + ((((size_t)(b * TT + t) * HEADS + h) * NN + n) << 6) + d] = f2bf(val);
        }
      }
    }
  }
}

// ---------------- V transpose: [slab][325][64] -> [slab][64][VTS], zero pad cols ----------------
__global__ __launch_bounds__(256) void vt_pack(const u16* __restrict__ v, u16* __restrict__ vt) {
  __shared__ u16 sv[325 * 66];
  int slab = blockIdx.x;            // (b*T + t)*H + h
  const u16* src = v + (size_t)slab * 325 * 64;
  u16* dst = vt + (size_t)slab * 64 * VTS;
  int tid = threadIdx.x;
  for (int i = tid; i < 325 * 16; i += 256) {
    int n = i >> 4, dd = (i & 15) * 4;
    uint2 w = *(const uint2*)(src + n * 64 + dd);
    *(uint*)(sv + n * 66 + dd) = w.x;
    *(uint*)(sv + n * 66 + dd + 2) = w.y;
  }
  __syncthreads();
  for (int d = 0; d < 64; ++d)
    for (int n = tid; n < VTS; n += 256)
      dst[d * VTS + n] = (n < NN) ? sv[n * 66 + d] : (u16)0;
}

// ---------------- MFMA attention, v3 ----------------
// Block = 4 waves = heads hg*4..hg*4+3 of one (b,t,ti,qt).
// adj tile (shared, head-independent) staged in LDS [64][36] f32, single buffer,
// loads issued one tile ahead (T14). K/VT per-wave global, register-prefetched
// one tile ahead. Fixed softmax shift (m=8), exp2-based. Swapped QK^T so P lands
// in the PV A-fragment with zero shuffles.
__global__ __launch_bounds__(256, 2) void attn(
    const u16* __restrict__ qkv,    // q at 0, k at QKV_ELE
    const u16* __restrict__ vt,     // [384][64][VTS]
    const float* __restrict__ adj,
    u16* __restrict__ hcat)         // [B][36][N][512] bf16
{
  __shared__ float sA[64 * 36];

  const int tid = threadIdx.x;
  const int wid = tid >> 6;
  const int lane = tid & 63;
  const int qi = lane & 15;
  const int g = lane >> 4;

  int blk = blockIdx.x;             // ((idx3)*6 + qt)*2 + hg
  int hg = blk & 1;
  int rest0 = blk >> 1;
  int qt = rest0 % 6;
  int idx3 = rest0 / 6;
  int ti = idx3 % 3;
  int bt = idx3 / 3;
  int t = bt % TT;
  int b = bt / TT;
  int h = hg * 4 + wid;

  const int c_kv[3]  = {9, 7, 6};       // k/v cumulative shifts: t-3, t-5, t-6
  const int c_adj[3] = {9, 10, 11};     // adj shifts: t-3, t-2, t-1
  const float qscA[3] = {0.125f, 0.015625f, 0.001953125f};
  int t_kv = (t + c_kv[ti]) % TT;
  int t_adj = (t + c_adj[ti]) % TT;
  float qsc = qscA[ti];
  int q0 = qt * 64;

  const u16* qbase  = qkv + ((((size_t)(b * TT + t) * HEADS + h) * NN) << 6);
  const u16* kbase  = qkv + QKV_ELE + ((((size_t)(b * TT + t_kv) * HEADS + h) * NN) << 6);
  const u16* vtbase = vt + (size_t)((b * TT + t_kv) * HEADS + h) * 64 * VTS;
  const float* adjbase = adj + (size_t)(b * TT + t_adj) * NN * NN;

  // Q fragments (B-operand): Q[q0+s*16+qi][g*8+e | 32+g*8+e]
  bf16x8 qf[4][2];
#pragma unroll
  for (int s = 0; s < 4; ++s) {
    int qr = q0 + s * 16 + qi; if (qr > NN - 1) qr = NN - 1;
    const u16* qp = qbase + qr * 64 + g * 8;
    qf[s][0] = *(const bf16x8*)qp;
    qf[s][1] = *(const bf16x8*)(qp + 32);
  }

  // adj staging: 256 threads x 2 float4 rows (sr1, sr1+32), chunk sc
  const int sr1 = tid >> 3;          // 0..31
  const int sr2 = sr1 + 32;
  const int sc = tid & 7;            // chunk of 4 floats
  int ar1 = q0 + sr1; if (ar1 > NN - 1) ar1 = NN - 1;
  int ar2 = q0 + sr2; if (ar2 > NN - 1) ar2 = NN - 1;
  const float* ap1 = adjbase + (size_t)ar1 * NN;
  const float* ap2 = adjbase + (size_t)ar2 * NN;

  const int rmap = ((qi >> 2) << 3) + (qi & 3);
  const f32x4 z4 = {0.f, 0.f, 0.f, 0.f};
  const float LG = 1.44269504f;
  const float C8 = -11.5415603f;     // -8*log2(e)

  f32x4 acc[4][4] = {};
  float lsum[4] = {0.f, 0.f, 0.f, 0.f};

  // ---- prolog: issue tile-0 loads ----
  float4 a1, a2;
  bf16x8 kc0, kc1, kc2, kc3, vc0, vc1, vc2, vc3;
  {
    a1 = *(const float4*)(ap1 + sc * 4);
    a2 = *(const float4*)(ap2 + sc * 4);
    const u16* kp0 = kbase + (size_t)rmap * 64 + g * 8;
    const u16* kp1 = kp0 + 4 * 64;
    kc0 = *(const bf16x8*)kp0;  kc1 = *(const bf16x8*)(kp0 + 32);
    kc2 = *(const bf16x8*)kp1;  kc3 = *(const bf16x8*)(kp1 + 32);
    const u16* vp = vtbase + qi * VTS + g * 8;
    vc0 = *(const bf16x8*)vp;
    vc1 = *(const bf16x8*)(vp + 16 * VTS);
    vc2 = *(const bf16x8*)(vp + 32 * VTS);
    vc3 = *(const bf16x8*)(vp + 48 * VTS);
  }

  for (int kt = 0; kt < 11; ++kt) {
    __syncthreads();                    // prior compute done reading sA
    *(float4*)&sA[sr1 * 36 + sc * 4] = a1;
    *(float4*)&sA[sr2 * 36 + sc * 4] = a2;
    __syncthreads();

    // issue next-tile loads (land during this tile's compute)
    bf16x8 kn0, kn1, kn2, kn3, vn0, vn1, vn2, vn3;
    if (kt < 10) {
      int K1 = (kt + 1) * 32;
      if (kt + 1 < 10) {
        a1 = *(const float4*)(ap1 + K1 + sc * 4);
        a2 = *(const float4*)(ap2 + K1 + sc * 4);
      } else {                           // tail tile: keys 320..324, rest zero
        float4 z = {0.f, 0.f, 0.f, 0.f};
        a1 = z; a2 = z;
        if (sc == 0) { a1 = *(const float4*)(ap1 + 320); a2 = *(const float4*)(ap2 + 320); }
        else if (sc == 1) { a1.x = ap1[324]; a2.x = ap2[324]; }
      }
      int r0 = K1 + rmap;     if (r0 > NN - 1) r0 = NN - 1;
      int r1 = K1 + rmap + 4; if (r1 > NN - 1) r1 = NN - 1;
      const u16* kp0 = kbase + (size_t)r0 * 64 + g * 8;
      const u16* kp1 = kbase + (size_t)r1 * 64 + g * 8;
      kn0 = *(const bf16x8*)kp0;  kn1 = *(const bf16x8*)(kp0 + 32);
      kn2 = *(const bf16x8*)kp1;  kn3 = *(const bf16x8*)(kp1 + 32);
      const u16* vp = vtbase + qi * VTS + K1 + g * 8;
      vn0 = *(const bf16x8*)vp;
      vn1 = *(const bf16x8*)(vp + 16 * VTS);
      vn2 = *(const bf16x8*)(vp + 32 * VTS);
      vn3 = *(const bf16x8*)(vp + 48 * VTS);
    }

    // ---- compute tile kt ----
#pragma unroll
    for (int s = 0; s < 4; ++s) {
      f32x4 s0 = MFMA(kc0, qf[s][0], z4);
      s0 = MFMA(kc1, qf[s][1], s0);
      f32x4 s1 = MFMA(kc2, qf[s][0], z4);
      s1 = MFMA(kc3, qf[s][1], s1);
      const float* arow = &sA[(s * 16 + qi) * 36 + g * 8];
      float4 fa = *(const float4*)arow;
      float4 fb = *(const float4*)(arow + 4);
      float p[8];
      {
        float av;
        av = fa.x; p[0] = EXP2(__builtin_fmaf(__builtin_fmaf(s0[0], av * qsc, av), LG, C8));
        av = fa.y; p[1] = EXP2(__builtin_fmaf(__builtin_fmaf(s0[1], av * qsc, av), LG, C8));
        av = fa.z; p[2] = EXP2(__builtin_fmaf(__builtin_fmaf(s0[2], av * qsc, av), LG, C8));
        av = fa.w; p[3] = EXP2(__builtin_fmaf(__builtin_fmaf(s0[3], av * qsc, av), LG, C8));
        av = fb.x; p[4] = EXP2(__builtin_fmaf(__builtin_fmaf(s1[0], av * qsc, av), LG, C8));
        av = fb.y; p[5] = EXP2(__builtin_fmaf(__builtin_fmaf(s1[1], av * qsc, av), LG, C8));
        av = fb.z; p[6] = EXP2(__builtin_fmaf(__builtin_fmaf(s1[2], av * qsc, av), LG, C8));
        av = fb.w; p[7] = EXP2(__builtin_fmaf(__builtin_fmaf(s1[3], av * qsc, av), LG, C8));
      }
      if (kt == 10) {
        // only keys 320..324 are real: slots ko=g*8+e valid iff ko<5
        float ps = 0.f;
        if (g == 0) ps = (((p[0] + p[1]) + (p[2] + p[3])) + p[4]);
        lsum[s] += ps;
      } else {
        lsum[s] += ((p[0] + p[1]) + (p[2] + p[3])) + ((p[4] + p[5]) + (p[6] + p[7]));
      }
      union { uint32_t u[4]; bf16x8 v; } pu;
      pu.u[0] = pk2(p[1], p[0]);
      pu.u[1] = pk2(p[3], p[2]);
      pu.u[2] = pk2(p[5], p[4]);
      pu.u[3] = pk2(p[7], p[6]);
      acc[s][0] = MFMA(pu.v, vc0, acc[s][0]);
      acc[s][1] = MFMA(pu.v, vc1, acc[s][1]);
      acc[s][2] = MFMA(pu.v, vc2, acc[s][2]);
      acc[s][3] = MFMA(pu.v, vc3, acc[s][3]);
    }

    kc0 = kn0; kc1 = kn1; kc2 = kn2; kc3 = kn3;
    vc0 = vn0; vc1 = vn1; vc2 = vn2; vc3 = vn3;
  }

  // ---- epilogue: normalize + store ----
  size_t hb = ((size_t)(b * 36 + ti * TT + t) * NN) << 9;
#pragma unroll
  for (int s = 0; s < 4; ++s) {
    float v = lsum[s];
    v += __shfl_xor(v, 16);
    v += __shfl_xor(v, 32);
    float linv = 1.0f / v;
#pragma unroll
    for (int j = 0; j < 4; ++j) {
      float li = __shfl(linv, g * 4 + j);
      int qrow = q0 + s * 16 + 4 * g + j;
      if (qrow < NN) {
        u16* op = hcat + hb + ((size_t)qrow << 9) + h * 64 + qi;
#pragma unroll
        for (int dt = 0; dt < 4; ++dt)
          op[dt * 16] = f2bf(acc[s][dt][j] * li);
      }
    }
  }
}

// ---------------- temporal mix + residual + LayerNorm ----------------
__global__ __launch_bounds__(256) void mix_ln(
    const u16* __restrict__ hcat,
    const float* __restrict__ Wd,   // [12][36]
    const float* __restrict__ bd,   // [12]
    const float* __restrict__ x,
    const float* __restrict__ gamma,
    const float* __restrict__ beta,
    float* __restrict__ out)
{
  __shared__ float sH[36 * 512];
  __shared__ float sWd[12 * 36];
  __shared__ float sred[8];
  int bn = blockIdx.x;
  int b = bn / NN, n = bn - b * NN;
  int tid = threadIdx.x;
  int lane = tid & 63, wid = tid >> 6;

  for (int i = tid; i < 12 * 36; i += 256) sWd[i] = Wd[i];
  for (int i = tid; i < 36 * 512; i += 256) {
    int w = i >> 9, d = i & 511;
    sH[i] = bf2f(hcat[(((size_t)(b * 36 + w) * NN + n) << 9) + d]);
  }
  __syncthreads();

  for (int t = 0; t < TT; ++t) {
    float a0 = 0.f, a1 = 0.f;
#pragma unroll
    for (int w = 0; w < 36; ++w) {
      float wv = sWd[t * 36 + w];
      a0 += sH[(w << 9) + tid] * wv;
      a1 += sH[(w << 9) + 256 + tid] * wv;
    }
    size_t xoff = ((size_t)(b * TT + t) * NN + n) << 9;
    float bdt = bd[t];
    float y0 = a0 + bdt + x[xoff + tid];
    float y1 = a1 + bdt + x[xoff + 256 + tid];
    float s = y0 + y1, ss = y0 * y0 + y1 * y1;
#pragma unroll
    for (int off = 32; off > 0; off >>= 1) {
      s += __shfl_down(s, off);
      ss += __shfl_down(ss, off);
    }
    if (lane == 0) { sred[wid * 2] = s; sred[wid * 2 + 1] = ss; }
    __syncthreads();
    float stot = sred[0] + sred[2] + sred[4] + sred[6];
    float sstot = sred[1] + sred[3] + sred[5] + sred[7];
    float mu = stot * (1.0f / 512.0f);
    float var = sstot * (1.0f / 512.0f) - mu * mu;
    float rstd = rsqrtf(var + 1e-5f);
    out[xoff + tid] = (y0 - mu) * rstd * gamma[tid] + beta[tid];
    out[xoff + 256 + tid] = (y1 - mu) * rstd * gamma[tid + 256] + beta[tid + 256];
    __syncthreads();
  }
}

extern "C" void kernel_launch(void* const* d_in, const int* in_sizes, int n_in,
                              void* d_out, int out_size, void* d_ws, size_t ws_size,
                              hipStream_t stream) {
  const float* x     = (const float*)d_in[0];
  const float* adj   = (const float*)d_in[1];
  // d_in[2] = s_adj: unused by the reference
  const float* Wq    = (const float*)d_in[3];
  const float* bq    = (const float*)d_in[4];
  const float* Wk    = (const float*)d_in[5];
  const float* bk    = (const float*)d_in[6];
  const float* Wv    = (const float*)d_in[7];
  const float* bv    = (const float*)d_in[8];
  const float* Wd    = (const float*)d_in[9];
  const float* bd    = (const float*)d_in[10];
  const float* gamma = (const float*)d_in[11];
  const float* beta  = (const float*)d_in[12];
  float* out = (float*)d_out;

  char* ws = (char*)d_ws;
  size_t off = 0;
  auto alloc = [&](size_t bytes) {
    void* p = ws + off;
    off += (bytes + 255) & ~(size_t)255;
    return p;
  };
  u16* Wb     = (u16*)alloc(1536 * 512 * 2);         // [Wq;Wk;Wv] bf16
  float* bias = (float*)alloc(1536 * 4);             // [bq;bk;bv]
  u16* qkv    = (u16*)alloc(3 * QKV_ELE * 2);        // q,k,v bf16 (B,T,H,N,64)
  u16* hcat   = (u16*)alloc(3 * QKV_ELE * 2);        // (B,36,N,512) bf16
  u16* vtb    = (u16*)alloc((size_t)BB * TT * HEADS * 64 * VTS * 2);  // V^T padded

  pack_w<<<dim3(768), dim3(256), 0, stream>>>(Wq, Wk, Wv, bq, bk, bv, Wb, bias);
  proj_gemm<<<dim3((MROWS + 127) / 128, 1536 / 128), dim3(256), 0, stream>>>(x, Wb, bias, qkv);
  vt_pack<<<dim3(BB * TT * HEADS), dim3(256), 0, stream>>>(qkv + 2 * QKV_ELE, vtb);
  attn<<<dim3(BB * TT * WIN * 6 * 2), dim3(256), 0, stream>>>(qkv, vtb, adj, hcat);
  mix_ln<<<dim3(BB * NN), dim3(256), 0, stream>>>(hcat, Wd, bd, x, gamma, beta, out);
}